// Round 15
// baseline (89.269 us; speedup 1.0000x reference)
//
#include <hip/hip_runtime.h>
#include <stdint.h>

#define NFEAT  128
#define NREL   3
#define BINCAP 5120   // slab capacity per 256-node bin; mean ~4096, +16 sigma safe

typedef short short8 __attribute__((ext_vector_type(8)));
typedef float f32x4  __attribute__((ext_vector_type(4)));
typedef unsigned int u32x4 __attribute__((ext_vector_type(4)));

// ---------- helpers ----------
__device__ __forceinline__ uint32_t f2bf(float x) {
    uint32_t u = __builtin_bit_cast(uint32_t, x);
    uint32_t r = (u + 0x7FFFu + ((u >> 16) & 1u)) >> 16;  // RNE
    return r & 0xFFFFu;
}
__device__ __forceinline__ float bf_lo(uint32_t v) {
    return __builtin_bit_cast(float, v << 16);
}
__device__ __forceinline__ float bf_hi(uint32_t v) {
    return __builtin_bit_cast(float, v & 0xFFFF0000u);
}

// ---------- K1: merged W-prep (blocks < WBn) + binfill (blocks >= WBn) ------
// Independent: prep writes Wt from W; binfill bins edges (bincursor pre-zeroed
// by hipMemsetAsync). record: (rowidx | dstlocal<<18, norm), rowidx = rel*N+src.
__global__ __launch_bounds__(256) void k_prep_fill(
    const float* __restrict__ W, uint16_t* __restrict__ Wt,
    const int* __restrict__ dst, const int* __restrict__ src,
    const int* __restrict__ rel, const float* __restrict__ norm,
    int* __restrict__ bincursor, uint2* __restrict__ binbuf,
    int N, int E, int WBn)
{
    const int t = threadIdx.x;

    if (blockIdx.x < (unsigned)WBn) {
        // ---------------- Wt transform ----------------
        const int tid = blockIdx.x * 256 + t;
        if (tid >= NREL * NFEAT * 16) return;
        const int k8 = tid & 15;
        const int o  = (tid >> 4) & 127;
        const int r  = tid >> 11;
        const float* Wr = W + (size_t)r * NFEAT * NFEAT;
        uint32_t pk[4];
        #pragma unroll
        for (int q = 0; q < 4; q++) {
            float lo = Wr[(size_t)(k8 * 8 + q * 2)     * NFEAT + o];
            float hi = Wr[(size_t)(k8 * 8 + q * 2 + 1) * NFEAT + o];
            pk[q] = f2bf(lo) | (f2bf(hi) << 16);
        }
        uint4 v = make_uint4(pk[0], pk[1], pk[2], pk[3]);
        *reinterpret_cast<uint4*>(&Wt[(size_t)r * NFEAT * NFEAT + (size_t)o * NFEAT + k8 * 8]) = v;
        return;
    }

    // ---------------- binfill (r13-proven, LDS-staged) ----------------
    __shared__ int hist[256];
    __shared__ int sm[256];
    __shared__ int binstart[256];
    __shared__ int gbase[256];
    __shared__ uint2 buf[2048];       // 16 KB staging
    __shared__ uint8_t binof[2048];   // 2 KB bin id per staged slot
    const int e0 = (blockIdx.x - WBn) * 2048;

    hist[t] = 0;
    __syncthreads();

    int myBin[8], myLoc[8];
    uint2 myRec[8];
    #pragma unroll
    for (int j = 0; j < 8; j++) {
        int e = e0 + j * 256 + t;
        myBin[j] = -1;
        if (e < E) {
            int d = dst[e];
            int b = d >> 8;
            myBin[j] = b;
            myLoc[j] = atomicAdd(&hist[b], 1);   // local rank within (block, bin)
            uint32_t rowidx = (uint32_t)(rel[e] * N + src[e]);   // < 150000
            myRec[j] = make_uint2(rowidx | ((uint32_t)(d & 255) << 18),
                                  __builtin_bit_cast(uint32_t, norm[e]));
        }
    }
    __syncthreads();

    const int v = hist[t];
    sm[t] = v;
    __syncthreads();
    for (int s = 1; s < 256; s <<= 1) {
        int a = (t >= s) ? sm[t - s] : 0;
        __syncthreads();
        sm[t] += a;
        __syncthreads();
    }
    binstart[t] = sm[t] - v;
    gbase[t] = (v > 0) ? atomicAdd(&bincursor[t], v) : 0;
    __syncthreads();

    #pragma unroll
    for (int j = 0; j < 8; j++) {
        if (myBin[j] >= 0) {
            int pos = binstart[myBin[j]] + myLoc[j];
            buf[pos] = myRec[j];
            binof[pos] = (uint8_t)myBin[j];
        }
    }
    __syncthreads();

    const int total = binstart[255] + hist[255];
    for (int i = t; i < total; i += 256) {
        int b = binof[i];
        int slot = gbase[b] + (i - binstart[b]);
        if (slot < BINCAP)
            binbuf[(size_t)b * BINCAP + slot] = buf[i];
    }
}

// ---------- K2: merged GEMM (blocks < GB) + binsort (blocks >= GB) ----------
__global__ __launch_bounds__(256) void k_gemm_sort(
    const float* __restrict__ feat, const uint16_t* __restrict__ Wt,
    uint16_t* __restrict__ hr, int N, int GB,
    const uint2* __restrict__ binbuf, const int* __restrict__ bincursor,
    uint2* __restrict__ meta, uint2* __restrict__ offs)
{
    __shared__ __align__(16) char smem[65536];
    const int t = threadIdx.x;

    if (blockIdx.x >= (unsigned)GB) {
        // ================= binsort path (r12-proven, LDS-staged) =================
        int* sm  = reinterpret_cast<int*>(smem);             // 1 KB
        int* cur = reinterpret_cast<int*>(smem + 1024);      // 1 KB
        uint2* buf = reinterpret_cast<uint2*>(smem + 2048);  // 40 KB
        const int b = blockIdx.x - GB;
        const int base = b * BINCAP;
        int cnt = bincursor[b];
        if (cnt > BINCAP) cnt = BINCAP;

        sm[t] = 0;
        __syncthreads();
        for (int i = t; i < cnt; i += 256) {
            uint2 r = binbuf[base + i];
            atomicAdd(&sm[(r.x >> 18) & 255], 1);
        }
        __syncthreads();
        int v = sm[t];
        __syncthreads();
        sm[t] = v;
        __syncthreads();
        for (int s = 1; s < 256; s <<= 1) {
            int a = (t >= s) ? sm[t - s] : 0;
            __syncthreads();
            sm[t] += a;
            __syncthreads();
        }
        int excl = sm[t] - v;
        int n = b * 256 + t;
        if (n < N) offs[n] = make_uint2(base + excl, base + excl + v);
        cur[t] = excl;
        __syncthreads();

        for (int i = t; i < cnt; i += 256) {
            uint2 r = binbuf[base + i];
            int dl = (r.x >> 18) & 255;
            int p = atomicAdd(&cur[dl], 1);
            buf[p] = make_uint2(r.x & 0x3FFFFu, r.y);   // rowidx only
        }
        __syncthreads();

        for (int i = t; i < cnt; i += 256)
            meta[base + i] = buf[i];
        return;
    }

    // ================= GEMM path (BM=128, a-frags hoisted) =================
    char* ldsA = smem;           // 32 KB, [row][k] swizzled
    char* ldsB = smem + 32768;   // 32 KB, [ocol][k] swizzled

    const int lane = t & 63;
    const int w    = t >> 6;
    const int n0   = blockIdx.x * 128;

    // stage A (fp32 -> bf16, swizzled): 128 rows, 16 rows/pass x 8 passes
    {
        const int kq = t & 15;
        const int rq = t >> 4;
        #pragma unroll
        for (int rr = 0; rr < 8; rr++) {
            const int row = rr * 16 + rq;
            const int n = n0 + row;
            uint4 pk = make_uint4(0, 0, 0, 0);
            if (n < N) {
                const float4* p = reinterpret_cast<const float4*>(&feat[(size_t)n * NFEAT + kq * 8]);
                float4 v0 = p[0], v1 = p[1];
                pk.x = f2bf(v0.x) | (f2bf(v0.y) << 16);
                pk.y = f2bf(v0.z) | (f2bf(v0.w) << 16);
                pk.z = f2bf(v1.x) | (f2bf(v1.y) << 16);
                pk.w = f2bf(v1.z) | (f2bf(v1.w) << 16);
            }
            uint32_t byte = (uint32_t)(row * 256 + kq * 16) ^ ((uint32_t)(row & 7) << 4);
            *reinterpret_cast<uint4*>(ldsA + byte) = pk;
        }
    }

    const int rowf = lane & 15;
    const int kb   = lane >> 4;

    short8 a[2][4];   // loaded once at r==0, reused for all relations

    for (int r = 0; r < NREL; r++) {
        // stage B = Wt[r] (bf16, swizzled)
        {
            const int kq = t & 15;
            const int rq = t >> 4;
            const uint16_t* Wr = Wt + (size_t)r * NFEAT * NFEAT;
            #pragma unroll
            for (int rr = 0; rr < 8; rr++) {
                const int row = rr * 16 + rq;
                uint4 v = *reinterpret_cast<const uint4*>(&Wr[(size_t)row * NFEAT + kq * 8]);
                uint32_t byte = (uint32_t)(row * 256 + kq * 16) ^ ((uint32_t)(row & 7) << 4);
                *reinterpret_cast<uint4*>(ldsB + byte) = v;
            }
        }
        __syncthreads();

        if (r == 0) {
            // A fragments once: ldsA is never overwritten
            #pragma unroll
            for (int rf = 0; rf < 2; rf++) {
                const int row = w * 32 + rf * 16 + rowf;
                #pragma unroll
                for (int ks = 0; ks < 4; ks++) {
                    uint32_t byte = (uint32_t)(row * 256 + ks * 64 + kb * 16) ^ ((uint32_t)(row & 7) << 4);
                    a[rf][ks] = *reinterpret_cast<const short8*>(ldsA + byte);
                }
            }
        }

        f32x4 acc[2][8];
        #pragma unroll
        for (int rf = 0; rf < 2; rf++)
            #pragma unroll
            for (int cf = 0; cf < 8; cf++) acc[rf][cf] = (f32x4){0.f, 0.f, 0.f, 0.f};

        #pragma unroll
        for (int cf = 0; cf < 8; cf++) {
            const int col = cf * 16 + rowf;
            #pragma unroll
            for (int ks = 0; ks < 4; ks++) {
                uint32_t byte = (uint32_t)(col * 256 + ks * 64 + kb * 16) ^ ((uint32_t)(col & 7) << 4);
                short8 b = *reinterpret_cast<const short8*>(ldsB + byte);
                acc[0][cf] = __builtin_amdgcn_mfma_f32_16x16x32_bf16(a[0][ks], b, acc[0][cf], 0, 0, 0);
                acc[1][cf] = __builtin_amdgcn_mfma_f32_16x16x32_bf16(a[1][ks], b, acc[1][cf], 0, 0, 0);
            }
        }

        // D layout: col = rowf, row = kb*4 + j (16 lanes x 2B consecutive)
        #pragma unroll
        for (int rf = 0; rf < 2; rf++) {
            #pragma unroll
            for (int cf = 0; cf < 8; cf++) {
                #pragma unroll
                for (int j = 0; j < 4; j++) {
                    const int n = n0 + w * 32 + rf * 16 + kb * 4 + j;
                    if (n < N)
                        hr[((size_t)r * N + n) * NFEAT + cf * 16 + rowf] = (uint16_t)f2bf(acc[rf][cf][j]);
                }
            }
        }
        __syncthreads();
    }
}

// ---------- K3: pull aggregation + ReLU, 4 edges per wave (16B/lane) ----------
__global__ __launch_bounds__(256) void k_aggregate(
    const uint16_t* __restrict__ hr, const uint2* __restrict__ offs,
    const uint64_t* __restrict__ meta, float* __restrict__ out, int N)
{
    const int wid  = threadIdx.x >> 6;
    const int lane = threadIdx.x & 63;
    const int n = blockIdx.x * 4 + wid;
    if (n >= N) return;

    const uint2 se = offs[n];
    int idx = (int)se.x;
    const int end = (int)se.y;

    const int g = lane >> 4;     // edge slot 0..3
    const int q = lane & 15;     // 16B column chunk
    const char* hrb = reinterpret_cast<const char*>(hr) + q * 16;

    float a0 = 0.f, a1 = 0.f, a2 = 0.f, a3 = 0.f;
    float a4 = 0.f, a5 = 0.f, a6 = 0.f, a7 = 0.f;

    for (; idx + 7 < end; idx += 8) {
        uint64_t m0 = __builtin_nontemporal_load(&meta[idx + g]);
        uint64_t m1 = __builtin_nontemporal_load(&meta[idx + 4 + g]);
        u32x4 v0 = *reinterpret_cast<const u32x4*>(hrb + ((size_t)(uint32_t)m0 << 8));
        u32x4 v1 = *reinterpret_cast<const u32x4*>(hrb + ((size_t)(uint32_t)m1 << 8));
        float w0 = __builtin_bit_cast(float, (uint32_t)(m0 >> 32));
        float w1 = __builtin_bit_cast(float, (uint32_t)(m1 >> 32));
        a0 += w0 * bf_lo(v0.x); a1 += w0 * bf_hi(v0.x);
        a2 += w0 * bf_lo(v0.y); a3 += w0 * bf_hi(v0.y);
        a4 += w0 * bf_lo(v0.z); a5 += w0 * bf_hi(v0.z);
        a6 += w0 * bf_lo(v0.w); a7 += w0 * bf_hi(v0.w);
        a0 += w1 * bf_lo(v1.x); a1 += w1 * bf_hi(v1.x);
        a2 += w1 * bf_lo(v1.y); a3 += w1 * bf_hi(v1.y);
        a4 += w1 * bf_lo(v1.z); a5 += w1 * bf_hi(v1.z);
        a6 += w1 * bf_lo(v1.w); a7 += w1 * bf_hi(v1.w);
    }
    for (; idx + 3 < end; idx += 4) {
        uint64_t m0 = __builtin_nontemporal_load(&meta[idx + g]);
        u32x4 v0 = *reinterpret_cast<const u32x4*>(hrb + ((size_t)(uint32_t)m0 << 8));
        float w0 = __builtin_bit_cast(float, (uint32_t)(m0 >> 32));
        a0 += w0 * bf_lo(v0.x); a1 += w0 * bf_hi(v0.x);
        a2 += w0 * bf_lo(v0.y); a3 += w0 * bf_hi(v0.y);
        a4 += w0 * bf_lo(v0.z); a5 += w0 * bf_hi(v0.z);
        a6 += w0 * bf_lo(v0.w); a7 += w0 * bf_hi(v0.w);
    }
    if (idx + g < end) {
        uint64_t m0 = __builtin_nontemporal_load(&meta[idx + g]);
        u32x4 v0 = *reinterpret_cast<const u32x4*>(hrb + ((size_t)(uint32_t)m0 << 8));
        float w0 = __builtin_bit_cast(float, (uint32_t)(m0 >> 32));
        a0 += w0 * bf_lo(v0.x); a1 += w0 * bf_hi(v0.x);
        a2 += w0 * bf_lo(v0.y); a3 += w0 * bf_hi(v0.y);
        a4 += w0 * bf_lo(v0.z); a5 += w0 * bf_hi(v0.z);
        a6 += w0 * bf_lo(v0.w); a7 += w0 * bf_hi(v0.w);
    }

    a0 += __shfl_xor(a0, 16); a1 += __shfl_xor(a1, 16);
    a2 += __shfl_xor(a2, 16); a3 += __shfl_xor(a3, 16);
    a4 += __shfl_xor(a4, 16); a5 += __shfl_xor(a5, 16);
    a6 += __shfl_xor(a6, 16); a7 += __shfl_xor(a7, 16);
    a0 += __shfl_xor(a0, 32); a1 += __shfl_xor(a1, 32);
    a2 += __shfl_xor(a2, 32); a3 += __shfl_xor(a3, 32);
    a4 += __shfl_xor(a4, 32); a5 += __shfl_xor(a5, 32);
    a6 += __shfl_xor(a6, 32); a7 += __shfl_xor(a7, 32);

    if (g == 0) {
        f32x4 o0, o1;
        o0[0] = fmaxf(a0, 0.f); o0[1] = fmaxf(a1, 0.f);
        o0[2] = fmaxf(a2, 0.f); o0[3] = fmaxf(a3, 0.f);
        o1[0] = fmaxf(a4, 0.f); o1[1] = fmaxf(a5, 0.f);
        o1[2] = fmaxf(a6, 0.f); o1[3] = fmaxf(a7, 0.f);
        f32x4* po = reinterpret_cast<f32x4*>(&out[(size_t)n * NFEAT + q * 8]);
        __builtin_nontemporal_store(o0, po);
        __builtin_nontemporal_store(o1, po + 1);
    }
}

// ---------- launch ----------
extern "C" void kernel_launch(void* const* d_in, const int* in_sizes, int n_in,
                              void* d_out, int out_size, void* d_ws, size_t ws_size,
                              hipStream_t stream)
{
    const float* feat = (const float*)d_in[0];
    const float* W    = (const float*)d_in[1];
    const float* norm = (const float*)d_in[2];
    const int*   src  = (const int*)d_in[3];
    const int*   dst  = (const int*)d_in[4];
    const int*   rel  = (const int*)d_in[5];
    float* out = (float*)d_out;

    const int N = in_sizes[0] / NFEAT;      // 50000
    const int E = in_sizes[2];              // 800000
    const int NBINS = (N + 255) / 256;      // 196
    const int HB  = (E + 2047) / 2048;      // 391 fill blocks
    const int GB  = (N + 127) / 128;        // 391 gemm blocks
    const int WBn = (NREL * NFEAT * 16 + 255) / 256;      // 24 Wt blocks

    char* ws = (char*)d_ws;
    size_t off = 0;
    auto alloc = [&](size_t bytes) -> char* {
        char* p = ws + off;
        off += (bytes + 63) & ~(size_t)63;
        return p;
    };
    uint16_t* hr    = (uint16_t*)alloc((size_t)NREL * N * NFEAT * 2);    // 38.4 MB
    uint16_t* Wt    = (uint16_t*)alloc((size_t)NREL * NFEAT * NFEAT * 2);
    int* bincursor  = (int*)alloc(256 * 4);
    uint2* offs     = (uint2*)alloc((size_t)N * 8);                      // 400 KB
    uint2* meta     = (uint2*)alloc((size_t)NBINS * BINCAP * 8);         // 8.0 MB
    (void)ws_size;

    // binbuf slab (8.0 MB) aliases d_out (25.6 MB): written by k_prep_fill, read
    // by merged k_gemm_sort; k_aggregate fully overwrites out afterwards.
    uint2* binbuf = (uint2*)d_out;

    hipMemsetAsync(bincursor, 0, 256 * sizeof(int), stream);
    k_prep_fill<<<WBn + HB, 256, 0, stream>>>(W, Wt, dst, src, rel, norm,
                                              bincursor, binbuf, N, E, WBn);
    k_gemm_sort<<<GB + NBINS, 256, 0, stream>>>(feat, Wt, hr, N, GB,
                                                binbuf, bincursor, meta, offs);
    k_aggregate<<<(N + 3) / 4, 256, 0, stream>>>(hr, offs, (const uint64_t*)meta, out, N);
}

// Round 16
// 88.238 us; speedup vs baseline: 1.0117x; 1.0117x over previous
//
#include <hip/hip_runtime.h>
#include <stdint.h>

#define NFEAT  128
#define NREL   3
#define BINCAP 5120   // slab capacity per 256-node bin; mean ~4096, +16 sigma safe

typedef short short8 __attribute__((ext_vector_type(8)));
typedef float f32x4  __attribute__((ext_vector_type(4)));
typedef unsigned int u32x4 __attribute__((ext_vector_type(4)));

// ---------- helpers ----------
__device__ __forceinline__ uint32_t f2bf(float x) {
    uint32_t u = __builtin_bit_cast(uint32_t, x);
    uint32_t r = (u + 0x7FFFu + ((u >> 16) & 1u)) >> 16;  // RNE
    return r & 0xFFFFu;
}
__device__ __forceinline__ float bf_lo(uint32_t v) {
    return __builtin_bit_cast(float, v << 16);
}
__device__ __forceinline__ float bf_hi(uint32_t v) {
    return __builtin_bit_cast(float, v & 0xFFFF0000u);
}

// ---------- K_prep: W->Wt bf16 [r][o][k] (coalesced) + zero bincursor ----------
__global__ __launch_bounds__(256) void k_prep(
    const float* __restrict__ W, uint16_t* __restrict__ Wt,
    int* __restrict__ bincursor, int WBn)
{
    const int t = threadIdx.x;
    if (blockIdx.x == (unsigned)WBn) {
        bincursor[t] = 0;
        return;
    }
    const int tid = blockIdx.x * 256 + t;
    if (tid >= NREL * NFEAT * 16) return;
    const int k8 = tid & 15;
    const int o  = (tid >> 4) & 127;
    const int r  = tid >> 11;
    const float* Wr = W + (size_t)r * NFEAT * NFEAT;
    uint32_t pk[4];
    #pragma unroll
    for (int q = 0; q < 4; q++) {
        float lo = Wr[(size_t)(k8 * 8 + q * 2)     * NFEAT + o];
        float hi = Wr[(size_t)(k8 * 8 + q * 2 + 1) * NFEAT + o];
        pk[q] = f2bf(lo) | (f2bf(hi) << 16);
    }
    uint4 v = make_uint4(pk[0], pk[1], pk[2], pk[3]);
    *reinterpret_cast<uint4*>(&Wt[(size_t)r * NFEAT * NFEAT + (size_t)o * NFEAT + k8 * 8]) = v;
}

// ---------- K2: bin-grouped fill, LDS-staged for coalesced slab writes ----------
// record: (rowidx | dstlocal<<18, norm)   rowidx = rel*N+src (18 bits)
__global__ __launch_bounds__(256) void k_binfill(
    const int* __restrict__ dst, const int* __restrict__ src,
    const int* __restrict__ rel, const float* __restrict__ norm,
    int* __restrict__ bincursor, uint2* __restrict__ binbuf, int N, int E)
{
    __shared__ int hist[256];
    __shared__ int sm[256];
    __shared__ int binstart[256];
    __shared__ int gbase[256];
    __shared__ uint2 buf[2048];       // 16 KB staging
    __shared__ uint8_t binof[2048];   // 2 KB bin id per staged slot
    const int t = threadIdx.x;
    const int e0 = blockIdx.x * 2048;

    hist[t] = 0;
    __syncthreads();

    int myBin[8], myLoc[8];
    uint2 myRec[8];
    #pragma unroll
    for (int j = 0; j < 8; j++) {
        int e = e0 + j * 256 + t;
        myBin[j] = -1;
        if (e < E) {
            int d = dst[e];
            int b = d >> 8;
            myBin[j] = b;
            myLoc[j] = atomicAdd(&hist[b], 1);   // local rank within (block, bin)
            uint32_t rowidx = (uint32_t)(rel[e] * N + src[e]);   // < 150000
            myRec[j] = make_uint2(rowidx | ((uint32_t)(d & 255) << 18),
                                  __builtin_bit_cast(uint32_t, norm[e]));
        }
    }
    __syncthreads();

    // exclusive scan of hist -> binstart; one global reserve per bin
    const int v = hist[t];
    sm[t] = v;
    __syncthreads();
    for (int s = 1; s < 256; s <<= 1) {
        int a = (t >= s) ? sm[t - s] : 0;
        __syncthreads();
        sm[t] += a;
        __syncthreads();
    }
    binstart[t] = sm[t] - v;
    gbase[t] = (v > 0) ? atomicAdd(&bincursor[t], v) : 0;
    __syncthreads();

    // stage into LDS in bin-sorted order
    #pragma unroll
    for (int j = 0; j < 8; j++) {
        if (myBin[j] >= 0) {
            int pos = binstart[myBin[j]] + myLoc[j];
            buf[pos] = myRec[j];
            binof[pos] = (uint8_t)myBin[j];
        }
    }
    __syncthreads();

    // coalesced write-out: thread i handles staged slot i
    const int total = binstart[255] + hist[255];
    for (int i = t; i < total; i += 256) {
        int b = binof[i];
        int slot = gbase[b] + (i - binstart[b]);
        if (slot < BINCAP)
            binbuf[(size_t)b * BINCAP + slot] = buf[i];
    }
}

// ---------- K3: merged GEMM (blocks < GB) + binsort (blocks >= GB) ----------
// Independent work overlapped in one launch; 64 KB LDS overlay shared by paths.
__global__ __launch_bounds__(256) void k_gemm_sort(
    const float* __restrict__ feat, const uint16_t* __restrict__ Wt,
    uint16_t* __restrict__ hr, int N, int GB,
    const uint2* __restrict__ binbuf, const int* __restrict__ bincursor,
    uint2* __restrict__ meta, uint2* __restrict__ offs)
{
    __shared__ __align__(16) char smem[65536];
    const int t = threadIdx.x;

    if (blockIdx.x >= (unsigned)GB) {
        // ================= binsort path (r12-proven, LDS-staged) =================
        int* sm  = reinterpret_cast<int*>(smem);             // 1 KB
        int* cur = reinterpret_cast<int*>(smem + 1024);      // 1 KB
        uint2* buf = reinterpret_cast<uint2*>(smem + 2048);  // 40 KB
        const int b = blockIdx.x - GB;
        const int base = b * BINCAP;
        int cnt = bincursor[b];
        if (cnt > BINCAP) cnt = BINCAP;

        sm[t] = 0;
        __syncthreads();
        for (int i = t; i < cnt; i += 256) {
            uint2 r = binbuf[base + i];
            atomicAdd(&sm[(r.x >> 18) & 255], 1);
        }
        __syncthreads();
        int v = sm[t];
        __syncthreads();
        sm[t] = v;
        __syncthreads();
        for (int s = 1; s < 256; s <<= 1) {
            int a = (t >= s) ? sm[t - s] : 0;
            __syncthreads();
            sm[t] += a;
            __syncthreads();
        }
        int excl = sm[t] - v;
        int n = b * 256 + t;
        if (n < N) offs[n] = make_uint2(base + excl, base + excl + v);
        cur[t] = excl;
        __syncthreads();

        for (int i = t; i < cnt; i += 256) {
            uint2 r = binbuf[base + i];
            int dl = (r.x >> 18) & 255;
            int p = atomicAdd(&cur[dl], 1);
            buf[p] = make_uint2(r.x & 0x3FFFFu, r.y);   // rowidx only
        }
        __syncthreads();

        for (int i = t; i < cnt; i += 256)
            meta[base + i] = buf[i];
        return;
    }

    // ================= GEMM path (r11/r13-proven, BM=128) =================
    char* ldsA = smem;           // 32 KB, [row][k] swizzled
    char* ldsB = smem + 32768;   // 32 KB, [ocol][k] swizzled

    const int lane = t & 63;
    const int w    = t >> 6;
    const int n0   = blockIdx.x * 128;

    // stage A (fp32 -> bf16, swizzled): 128 rows, 16 rows/pass x 8 passes
    {
        const int kq = t & 15;
        const int rq = t >> 4;
        #pragma unroll
        for (int rr = 0; rr < 8; rr++) {
            const int row = rr * 16 + rq;
            const int n = n0 + row;
            uint4 pk = make_uint4(0, 0, 0, 0);
            if (n < N) {
                const float4* p = reinterpret_cast<const float4*>(&feat[(size_t)n * NFEAT + kq * 8]);
                float4 v0 = p[0], v1 = p[1];
                pk.x = f2bf(v0.x) | (f2bf(v0.y) << 16);
                pk.y = f2bf(v0.z) | (f2bf(v0.w) << 16);
                pk.z = f2bf(v1.x) | (f2bf(v1.y) << 16);
                pk.w = f2bf(v1.z) | (f2bf(v1.w) << 16);
            }
            uint32_t byte = (uint32_t)(row * 256 + kq * 16) ^ ((uint32_t)(row & 7) << 4);
            *reinterpret_cast<uint4*>(ldsA + byte) = pk;
        }
    }

    const int rowf = lane & 15;
    const int kb   = lane >> 4;

    for (int r = 0; r < NREL; r++) {
        // stage B = Wt[r] (bf16, swizzled)
        {
            const int kq = t & 15;
            const int rq = t >> 4;
            const uint16_t* Wr = Wt + (size_t)r * NFEAT * NFEAT;
            #pragma unroll
            for (int rr = 0; rr < 8; rr++) {
                const int row = rr * 16 + rq;
                uint4 v = *reinterpret_cast<const uint4*>(&Wr[(size_t)row * NFEAT + kq * 8]);
                uint32_t byte = (uint32_t)(row * 256 + kq * 16) ^ ((uint32_t)(row & 7) << 4);
                *reinterpret_cast<uint4*>(ldsB + byte) = v;
            }
        }
        __syncthreads();

        // A fragments: 2 row-frags per wave (rows w*32 + rf*16 + rowf)
        short8 a[2][4];
        #pragma unroll
        for (int rf = 0; rf < 2; rf++) {
            const int row = w * 32 + rf * 16 + rowf;
            #pragma unroll
            for (int ks = 0; ks < 4; ks++) {
                uint32_t byte = (uint32_t)(row * 256 + ks * 64 + kb * 16) ^ ((uint32_t)(row & 7) << 4);
                a[rf][ks] = *reinterpret_cast<const short8*>(ldsA + byte);
            }
        }

        f32x4 acc[2][8];
        #pragma unroll
        for (int rf = 0; rf < 2; rf++)
            #pragma unroll
            for (int cf = 0; cf < 8; cf++) acc[rf][cf] = (f32x4){0.f, 0.f, 0.f, 0.f};

        #pragma unroll
        for (int cf = 0; cf < 8; cf++) {
            const int col = cf * 16 + rowf;
            #pragma unroll
            for (int ks = 0; ks < 4; ks++) {
                uint32_t byte = (uint32_t)(col * 256 + ks * 64 + kb * 16) ^ ((uint32_t)(col & 7) << 4);
                short8 b = *reinterpret_cast<const short8*>(ldsB + byte);
                acc[0][cf] = __builtin_amdgcn_mfma_f32_16x16x32_bf16(a[0][ks], b, acc[0][cf], 0, 0, 0);
                acc[1][cf] = __builtin_amdgcn_mfma_f32_16x16x32_bf16(a[1][ks], b, acc[1][cf], 0, 0, 0);
            }
        }

        // D layout: col = rowf, row = kb*4 + j (16 lanes x 2B consecutive)
        #pragma unroll
        for (int rf = 0; rf < 2; rf++) {
            #pragma unroll
            for (int cf = 0; cf < 8; cf++) {
                #pragma unroll
                for (int j = 0; j < 4; j++) {
                    const int n = n0 + w * 32 + rf * 16 + kb * 4 + j;
                    if (n < N)
                        hr[((size_t)r * N + n) * NFEAT + cf * 16 + rowf] = (uint16_t)f2bf(acc[rf][cf][j]);
                }
            }
        }
        __syncthreads();
    }
}

// ---------- K4: pull aggregation + ReLU, 4 edges per wave (16B/lane) ----------
__global__ __launch_bounds__(256) void k_aggregate(
    const uint16_t* __restrict__ hr, const uint2* __restrict__ offs,
    const uint64_t* __restrict__ meta, float* __restrict__ out, int N)
{
    const int wid  = threadIdx.x >> 6;
    const int lane = threadIdx.x & 63;
    const int n = blockIdx.x * 4 + wid;
    if (n >= N) return;

    const uint2 se = offs[n];
    int idx = (int)se.x;
    const int end = (int)se.y;

    const int g = lane >> 4;     // edge slot 0..3
    const int q = lane & 15;     // 16B column chunk
    const char* hrb = reinterpret_cast<const char*>(hr) + q * 16;

    float a0 = 0.f, a1 = 0.f, a2 = 0.f, a3 = 0.f;
    float a4 = 0.f, a5 = 0.f, a6 = 0.f, a7 = 0.f;

    for (; idx + 7 < end; idx += 8) {
        uint64_t m0 = __builtin_nontemporal_load(&meta[idx + g]);
        uint64_t m1 = __builtin_nontemporal_load(&meta[idx + 4 + g]);
        u32x4 v0 = *reinterpret_cast<const u32x4*>(hrb + ((size_t)(uint32_t)m0 << 8));
        u32x4 v1 = *reinterpret_cast<const u32x4*>(hrb + ((size_t)(uint32_t)m1 << 8));
        float w0 = __builtin_bit_cast(float, (uint32_t)(m0 >> 32));
        float w1 = __builtin_bit_cast(float, (uint32_t)(m1 >> 32));
        a0 += w0 * bf_lo(v0.x); a1 += w0 * bf_hi(v0.x);
        a2 += w0 * bf_lo(v0.y); a3 += w0 * bf_hi(v0.y);
        a4 += w0 * bf_lo(v0.z); a5 += w0 * bf_hi(v0.z);
        a6 += w0 * bf_lo(v0.w); a7 += w0 * bf_hi(v0.w);
        a0 += w1 * bf_lo(v1.x); a1 += w1 * bf_hi(v1.x);
        a2 += w1 * bf_lo(v1.y); a3 += w1 * bf_hi(v1.y);
        a4 += w1 * bf_lo(v1.z); a5 += w1 * bf_hi(v1.z);
        a6 += w1 * bf_lo(v1.w); a7 += w1 * bf_hi(v1.w);
    }
    for (; idx + 3 < end; idx += 4) {
        uint64_t m0 = __builtin_nontemporal_load(&meta[idx + g]);
        u32x4 v0 = *reinterpret_cast<const u32x4*>(hrb + ((size_t)(uint32_t)m0 << 8));
        float w0 = __builtin_bit_cast(float, (uint32_t)(m0 >> 32));
        a0 += w0 * bf_lo(v0.x); a1 += w0 * bf_hi(v0.x);
        a2 += w0 * bf_lo(v0.y); a3 += w0 * bf_hi(v0.y);
        a4 += w0 * bf_lo(v0.z); a5 += w0 * bf_hi(v0.z);
        a6 += w0 * bf_lo(v0.w); a7 += w0 * bf_hi(v0.w);
    }
    if (idx + g < end) {
        uint64_t m0 = __builtin_nontemporal_load(&meta[idx + g]);
        u32x4 v0 = *reinterpret_cast<const u32x4*>(hrb + ((size_t)(uint32_t)m0 << 8));
        float w0 = __builtin_bit_cast(float, (uint32_t)(m0 >> 32));
        a0 += w0 * bf_lo(v0.x); a1 += w0 * bf_hi(v0.x);
        a2 += w0 * bf_lo(v0.y); a3 += w0 * bf_hi(v0.y);
        a4 += w0 * bf_lo(v0.z); a5 += w0 * bf_hi(v0.z);
        a6 += w0 * bf_lo(v0.w); a7 += w0 * bf_hi(v0.w);
    }

    a0 += __shfl_xor(a0, 16); a1 += __shfl_xor(a1, 16);
    a2 += __shfl_xor(a2, 16); a3 += __shfl_xor(a3, 16);
    a4 += __shfl_xor(a4, 16); a5 += __shfl_xor(a5, 16);
    a6 += __shfl_xor(a6, 16); a7 += __shfl_xor(a7, 16);
    a0 += __shfl_xor(a0, 32); a1 += __shfl_xor(a1, 32);
    a2 += __shfl_xor(a2, 32); a3 += __shfl_xor(a3, 32);
    a4 += __shfl_xor(a4, 32); a5 += __shfl_xor(a5, 32);
    a6 += __shfl_xor(a6, 32); a7 += __shfl_xor(a7, 32);

    if (g == 0) {
        f32x4 o0, o1;
        o0[0] = fmaxf(a0, 0.f); o0[1] = fmaxf(a1, 0.f);
        o0[2] = fmaxf(a2, 0.f); o0[3] = fmaxf(a3, 0.f);
        o1[0] = fmaxf(a4, 0.f); o1[1] = fmaxf(a5, 0.f);
        o1[2] = fmaxf(a6, 0.f); o1[3] = fmaxf(a7, 0.f);
        f32x4* po = reinterpret_cast<f32x4*>(&out[(size_t)n * NFEAT + q * 8]);
        __builtin_nontemporal_store(o0, po);
        __builtin_nontemporal_store(o1, po + 1);
    }
}

// ---------- launch ----------
extern "C" void kernel_launch(void* const* d_in, const int* in_sizes, int n_in,
                              void* d_out, int out_size, void* d_ws, size_t ws_size,
                              hipStream_t stream)
{
    const float* feat = (const float*)d_in[0];
    const float* W    = (const float*)d_in[1];
    const float* norm = (const float*)d_in[2];
    const int*   src  = (const int*)d_in[3];
    const int*   dst  = (const int*)d_in[4];
    const int*   rel  = (const int*)d_in[5];
    float* out = (float*)d_out;

    const int N = in_sizes[0] / NFEAT;      // 50000
    const int E = in_sizes[2];              // 800000
    const int NBINS = (N + 255) / 256;      // 196
    const int HB  = (E + 2047) / 2048;      // 391 fill blocks
    const int GB  = (N + 127) / 128;        // 391 gemm blocks
    const int WBn = (NREL * NFEAT * 16 + 255) / 256;      // 24 Wt blocks

    char* ws = (char*)d_ws;
    size_t off = 0;
    auto alloc = [&](size_t bytes) -> char* {
        char* p = ws + off;
        off += (bytes + 63) & ~(size_t)63;
        return p;
    };
    uint16_t* hr    = (uint16_t*)alloc((size_t)NREL * N * NFEAT * 2);    // 38.4 MB
    uint16_t* Wt    = (uint16_t*)alloc((size_t)NREL * NFEAT * NFEAT * 2);
    int* bincursor  = (int*)alloc(256 * 4);
    uint2* offs     = (uint2*)alloc((size_t)N * 8);                      // 400 KB
    uint2* meta     = (uint2*)alloc((size_t)NBINS * BINCAP * 8);         // 8.0 MB
    (void)ws_size;

    // binbuf slab (8.0 MB) aliases d_out (25.6 MB): written by k_binfill, read
    // by merged k_gemm_sort; k_aggregate fully overwrites out afterwards.
    uint2* binbuf = (uint2*)d_out;

    k_prep<<<WBn + 1, 256, 0, stream>>>(W, Wt, bincursor, WBn);
    k_binfill<<<HB, 256, 0, stream>>>(dst, src, rel, norm, bincursor, binbuf, N, E);
    k_gemm_sort<<<GB + NBINS, 256, 0, stream>>>(feat, Wt, hr, N, GB,
                                                binbuf, bincursor, meta, offs);
    k_aggregate<<<(N + 3) / 4, 256, 0, stream>>>(hr, offs, (const uint64_t*)meta, out, N);
}